// Round 8
// baseline (356.568 us; speedup 1.0000x reference)
//
#include <hip/hip_runtime.h>

typedef unsigned short u16;
typedef unsigned int u32;
typedef __attribute__((ext_vector_type(8))) __bf16 bf16x8;
typedef __attribute__((ext_vector_type(8))) u16 u16x8;
typedef __attribute__((ext_vector_type(4))) float f32x4;
typedef __attribute__((ext_vector_type(2))) u32 u32x2;

__device__ __forceinline__ u16 f2bf(float f) {
  u32 u = __builtin_bit_cast(u32, f);
  u = (u + 0x7FFFu + ((u >> 16) & 1u)) >> 16;
  return (u16)u;
}

__device__ __forceinline__ f32x4 mfma16(bf16x8 a, bf16x8 b, f32x4 c) {
  return __builtin_amdgcn_mfma_f32_16x16x32_bf16(a, b, c, 0, 0, 0);
}

// ---------- NCHW f32 -> NHWC bf16 transpose of x ----------
__global__ __launch_bounds__(256) void k_tr(const float* __restrict__ x,
                                            u16* __restrict__ xh) {
  __shared__ float t[64][33];
  const int b = blockIdx.z, y = blockIdx.y, x0 = blockIdx.x * 32;
  const int tid = threadIdx.x;
  {
    int ic = tid >> 2, xo = (tid & 3) * 8;
    const float* s = x + (((size_t)b * 64 + ic) * 256 + y) * 256 + x0 + xo;
    f32x4 v0 = *(const f32x4*)s;
    f32x4 v1 = *(const f32x4*)(s + 4);
#pragma unroll
    for (int j = 0; j < 4; ++j) { t[ic][xo + j] = v0[j]; t[ic][xo + 4 + j] = v1[j]; }
  }
  __syncthreads();
  {
    int xc = tid >> 3, ic0 = (tid & 7) * 8;
    u16x8 v;
#pragma unroll
    for (int j = 0; j < 8; ++j) v[j] = f2bf(t[ic0 + j][xc]);
    *(u16x8*)(xh + (((size_t)b * 256 + y) * 256 + x0 + xc) * 64 + ic0) = v;
  }
}

// ---------- conv2/3 weights: [OC][IC][3][3] f32 -> [oc][tap*IC+icp] bf16 ----------
// perm=1: input channels arrive permuted as icp = (ic&15)*2 + (ic>>4)  (IC=32)
__global__ void k_prep_cw(const float* __restrict__ src, u16* __restrict__ dst,
                          int IC, int KK2, int n, int perm) {
  int d = blockIdx.x * 256 + threadIdx.x;
  if (d >= n) return;
  int per = KK2 * IC;
  int oc = d / per, r = d - oc * per;
  int tap = r / IC, icp = r - tap * IC;
  int ic = perm ? ((icp >> 1) + (icp & 1) * 16) : icp;
  dst[d] = f2bf(src[(oc * IC + ic) * KK2 + tap]);
}

// ---------- conv1 weights: [32][64][7][7] f32 -> [oc][tap(50, zero-pad)][ic(64)] bf16 ----------
__global__ void k_prep_cw1(const float* __restrict__ src, u16* __restrict__ dst) {
  int d = blockIdx.x * 256 + threadIdx.x;  // 32*3200
  if (d >= 32 * 3200) return;
  int oc = d / 3200, r = d - oc * 3200;
  int tap = r >> 6, ic = r & 63;
  float v = (tap < 49) ? src[(oc * 64 + ic) * 49 + tap] : 0.f;
  dst[d] = f2bf(v);
}

// ---------- HDA weights: merge dyn*ow | share (optionally *a) -> [b][oc][576] bf16 ----------
// perm=1 (stage 2): k-slot icp holds real channel ic = (icp&3)*16 + (icp>>2)
__global__ void k_prep_hda(const float* __restrict__ dyn, const float* __restrict__ ow,
                           const float* __restrict__ share, const float* __restrict__ a_,
                           u16* __restrict__ dst, int use_a, int perm) {
  int d = blockIdx.x * 256 + threadIdx.x;
  if (d >= 8 * 64 * 576) return;
  int b = d / 36864, r = d - b * 36864;
  int oc = r / 576, k = r - oc * 576;
  int tap = k >> 6, icp = k & 63;
  int ic = perm ? ((icp & 3) * 16 + (icp >> 2)) : icp;
  float v = (oc < 32) ? dyn[(oc * 64 + ic) * 9 + tap] * ow[((b * 32 + oc) * 64 + ic) * 9 + tap]
                      : share[((oc - 32) * 64 + ic) * 9 + tap];
  if (use_a) v *= a_[b * 64 + oc];
  dst[d] = f2bf(v);
}

// ---------- cond conv1: 7x7 s2 p1 64->32, MFMA ----------
// A (22x37 pos x 16ic chunk, 26KB LDS, swizzled) staged; W from global (L2-resident).
// 8y x 16x output tile, 1024 blocks XCD-swizzled, 4 blocks/CU.
// out: [8][126][126][32] bf16, PERMUTED channel order ic' = col*2 + nf
__global__ __launch_bounds__(256, 4) void k_cond1_mfma(const u16* __restrict__ xh,
    const u16* __restrict__ wgt /*[32][3200]*/, const float* __restrict__ cb,
    u16* __restrict__ dst) {
  __shared__ char lds[26112];  // 22*37=814 pos x 32B, swizzled
  // bijective XCD swizzle: 1024 = 8 XCDs x 128; each XCD owns one batch
  const int wg0 = blockIdx.x;
  const int wg = ((wg0 & 7) << 7) | (wg0 >> 3);
  const int b = wg >> 7, rr = wg & 127;
  const int oh0 = (rr >> 3) * 8, ow0 = (rr & 7) * 16;
  const int tid = threadIdx.x, lane = tid & 63, wid = tid >> 6;
  const int col = lane & 15, kq = lane >> 4;
  const int ihs = 2 * oh0 - 1, iws = 2 * ow0 - 1;
  const u16x8 Z = (u16x8)0;
  f32x4 acc[2][2];
#pragma unroll
  for (int i = 0; i < 2; ++i)
#pragma unroll
    for (int j = 0; j < 2; ++j) acc[i][j] = 0.f;
#pragma unroll 1
  for (int c = 0; c < 4; ++c) {  // 16-ic chunks
    __syncthreads();
    for (int i = tid; i < 1628; i += 256) {  // 814 pos x 2 halves
      int pos = i >> 1, half = i & 1;
      int r = pos / 37, cc = pos - r * 37;
      int gy = ihs + r, gx = iws + cc;
      u16x8 v = Z;
      if ((unsigned)gy < 256u && (unsigned)gx < 256u)
        v = *(const u16x8*)(xh + (((size_t)b * 256 + gy) * 256 + gx) * 64 + c * 16 + half * 8);
      int off = (pos * 32 + half * 16) ^ (((pos >> 1) & 7) << 4);
      *(u16x8*)(lds + off) = v;
    }
    __syncthreads();
#pragma unroll
    for (int s = 0; s < 25; ++s) {  // K-step: taps 2s (kq<2) | 2s+1 (kq>=2)
      const int t0 = 2 * s, t1 = 2 * s + 1;
      const int kh0 = t0 / 7, kw0 = t0 % 7;
      const int kh1 = t1 / 7, kw1 = t1 % 7;
      int hi = kq >> 1;
      int kh = hi ? kh1 : kh0;
      int kw = hi ? kw1 : kw0;
      int tap = hi ? t1 : t0;
      int hoff = (kq & 1) * 16;
      bf16x8 a[2];
#pragma unroll
      for (int mf = 0; mf < 2; ++mf) {
        int py = wid * 2 + mf;
        int pos = (2 * py + kh) * 37 + 2 * col + kw;
        int off = (pos * 32 + hoff) ^ (((pos >> 1) & 7) << 4);
        a[mf] = __builtin_bit_cast(bf16x8, *(const u16x8*)(lds + off));
      }
      bf16x8 w[2];
#pragma unroll
      for (int nf = 0; nf < 2; ++nf)
        w[nf] = __builtin_bit_cast(bf16x8,
            *(const u16x8*)(wgt + (nf * 16 + col) * 3200 + tap * 64 + c * 16 + (kq & 1) * 8));
#pragma unroll
      for (int mf = 0; mf < 2; ++mf)
#pragma unroll
        for (int nf = 0; nf < 2; ++nf) acc[mf][nf] = mfma16(a[mf], w[nf], acc[mf][nf]);
    }
  }
  const float bv0 = cb[col], bv1 = cb[16 + col];
#pragma unroll
  for (int mf = 0; mf < 2; ++mf) {
    int oh = oh0 + wid * 2 + mf;
    if (oh >= 126) continue;
#pragma unroll
    for (int r = 0; r < 4; ++r) {
      int ow = ow0 + kq * 4 + r;
      if (ow >= 126) continue;
      u32 pack = (u32)f2bf(fmaxf(acc[mf][0][r] + bv0, 0.f)) |
                 ((u32)f2bf(fmaxf(acc[mf][1][r] + bv1, 0.f)) << 16);
      *(u32*)(dst + (((size_t)b * 126 + oh) * 126 + ow) * 32 + col * 2) = pack;
    }
  }
}

// ---------- generic stride-2 pad-1 conv (small conv2/conv3) ----------
template <int HI, int HO, int IC, int KK, int OUTF32>
__global__ __launch_bounds__(256, 4) void k_conv_s2(const u16* __restrict__ src,
    const u16* __restrict__ wgt, const float* __restrict__ bias, void* __restrict__ dst) {
  const int b = blockIdx.z;
  const int by0 = blockIdx.y * 8, bx0 = blockIdx.x * 16;
  const int tid = threadIdx.x, lane = tid & 63, wid = tid >> 6;
  const int col = lane & 15, kq = lane >> 4;
  f32x4 acc[2][2];
#pragma unroll
  for (int i = 0; i < 2; ++i)
#pragma unroll
    for (int j = 0; j < 2; ++j) acc[i][j] = 0.f;
  const u16x8 Z = (u16x8)0;
#pragma unroll
  for (int kh = 0; kh < KK; ++kh) {
#pragma unroll
    for (int kw = 0; kw < KK; ++kw) {
#pragma unroll
      for (int h = 0; h < IC / 32; ++h) {
        bf16x8 a[2];
#pragma unroll
        for (int mf = 0; mf < 2; ++mf) {
          int oh = by0 + wid * 2 + mf;
          int ih = 2 * oh - 1 + kh;
          int ix = 2 * (bx0 + col) - 1 + kw;
          int ic = h * 32 + kq * 8;
          u16x8 raw = Z;
          if ((unsigned)ih < (unsigned)HI && (unsigned)ix < (unsigned)HI)
            raw = *(const u16x8*)(src + (((size_t)b * HI + ih) * HI + ix) * IC + ic);
          a[mf] = __builtin_bit_cast(bf16x8, raw);
        }
        int k0 = (kh * KK + kw) * IC + h * 32 + kq * 8;
        bf16x8 w[2];
#pragma unroll
        for (int nf = 0; nf < 2; ++nf)
          w[nf] = __builtin_bit_cast(bf16x8,
                    *(const u16x8*)(wgt + (size_t)(nf * 16 + col) * (KK * KK * IC) + k0));
#pragma unroll
        for (int mf = 0; mf < 2; ++mf)
#pragma unroll
          for (int nf = 0; nf < 2; ++nf) acc[mf][nf] = mfma16(a[mf], w[nf], acc[mf][nf]);
      }
    }
  }
#pragma unroll
  for (int mf = 0; mf < 2; ++mf) {
    int oh = by0 + wid * 2 + mf;
    if (oh >= HO) continue;
#pragma unroll
    for (int nf = 0; nf < 2; ++nf) {
      int oc = nf * 16 + col;
      float bv = bias[oc];
#pragma unroll
      for (int r = 0; r < 4; ++r) {
        int ow = bx0 + kq * 4 + r;
        if (ow >= HO) continue;
        float v = fmaxf(acc[mf][nf][r] + bv, 0.f);
        if (OUTF32)
          ((float*)dst)[(((size_t)b * 32 + oc) * HO + oh) * HO + ow] = v;
        else
          ((u16*)dst)[(((size_t)b * HO + oh) * HO + ow) * 32 + oc] = f2bf(v);
      }
    }
  }
}

// ---------- mean over 32x32 -> cond[8*32] ----------
__global__ void k_mean(const float* __restrict__ h3, float* __restrict__ cond) {
  int bo = blockIdx.x;
  int tid = threadIdx.x;
  float s = 0.f;
  for (int i = tid; i < 1024; i += 256) s += h3[bo * 1024 + i];
  __shared__ float red[256];
  red[tid] = s;
  __syncthreads();
  for (int o = 128; o > 0; o >>= 1) {
    if (tid < o) red[tid] += red[tid + o];
    __syncthreads();
  }
  if (tid == 0) cond[bo] = red[0] * (1.f / 1024.f);
}

// ---------- FiLM fold ----------
__global__ void k_film(const float* __restrict__ cond,
                       const float* __restrict__ scale_w, const float* __restrict__ scale_b,
                       const float* __restrict__ shift_w, const float* __restrict__ shift_b,
                       const float* __restrict__ share1_b, const float* __restrict__ share2_b,
                       float* __restrict__ a_, float* __restrict__ bias1,
                       float* __restrict__ bias2) {
  int t = threadIdx.x;  // 512
  int b = t >> 6, j = t & 63;
  float s = scale_b[j], sh = shift_b[j];
  for (int k = 0; k < 32; ++k) {
    float c = cond[b * 32 + k];
    s = fmaf(c, scale_w[j * 32 + k], s);
    sh = fmaf(c, shift_w[j * 32 + k], sh);
  }
  float a = s + 1.f;
  float b0 = (j < 32) ? 0.f : share1_b[j - 32];
  a_[t] = a;
  bias1[t] = fmaf(a, b0, sh);
  bias2[t] = (j < 32) ? 0.f : share2_b[j - 32];
}

// ---------- HDA conv 3x3 s1 p1 64->64, MFMA ----------
// A-tile (18x18x64, 41.5KB, swizzled) + W half (592B-padded stripes, 37.9KB) in LDS.
// STAGE 1: dst = NHWC bf16 relu(conv+bias), PERMUTED ic' = col*4+nf -> 8B coalesced stores
// STAGE 2: dst = NCHW f32 resid+conv+bias  (weights pre-permuted to match midh order)
template <int STAGE>
__global__ __launch_bounds__(256, 2) void k_hda_mfma(const u16* __restrict__ asrc,
    const u16* __restrict__ wall, const float* __restrict__ bias,
    const float* __restrict__ resid, void* __restrict__ dst) {
  __shared__ char lds[79360];  // [0,41472): A tile; [41472,79360): W half (64 x 592B)
  const int wg0 = blockIdx.x;
  const int wg = ((wg0 & 7) << 8) + (wg0 >> 3);
  const int b = wg >> 8;
  const int rr = wg & 255;
  const int by0 = (rr >> 4) << 4, bx0 = (rr & 15) << 4;
  const int tid = threadIdx.x, lane = tid & 63, wid = tid >> 6;
  const int col = lane & 15, kq = lane >> 4;
  const u16x8 Z = (u16x8)0;
  const u16* wb = wall + (size_t)b * 64 * 576;
  // stage input tile (all 64 ic)
  for (int i = tid; i < 2592; i += 256) {
    int L = i >> 3, c = i & 7;
    int yy = L / 18, xx = L - yy * 18;
    int gy = by0 - 1 + yy, gx = bx0 - 1 + xx;
    u16x8 v = Z;
    if ((unsigned)gy < 256u && (unsigned)gx < 256u)
      v = *(const u16x8*)(asrc + (((size_t)b * 256 + gy) * 256 + gx) * 64 + c * 8);
    int off = (L * 128 + c * 16) ^ ((L & 7) << 4);
    *(u16x8*)(lds + off) = v;
  }
  // stage weight half h=0 (592B stripe per oc)
  {
    int i = tid;
#pragma unroll
    for (int it = 0; it < 9; ++it, i += 256) {  // 2304 = 9*256 exact
      int oc = i / 36, s = i - oc * 36;
      int tap = s >> 2, q = s & 3;
      u16x8 v = *(const u16x8*)(wb + oc * 576 + tap * 64 + q * 8);
      int off = 41472 + oc * 592 + s * 16;
      *(u16x8*)(lds + off) = v;
    }
  }
  __syncthreads();
  f32x4 acc[4][4];
#pragma unroll
  for (int i = 0; i < 4; ++i)
#pragma unroll
    for (int j = 0; j < 4; ++j) acc[i][j] = 0.f;
#pragma unroll 1
  for (int h = 0; h < 2; ++h) {
    if (h == 1) {
      __syncthreads();  // h=0 reads done
      int i = tid;
#pragma unroll
      for (int it = 0; it < 9; ++it, i += 256) {
        int oc = i / 36, s = i - oc * 36;
        int tap = s >> 2, q = s & 3;
        u16x8 v = *(const u16x8*)(wb + oc * 576 + tap * 64 + 32 + q * 8);
        int off = 41472 + oc * 592 + s * 16;
        *(u16x8*)(lds + off) = v;
      }
      __syncthreads();
    }
#pragma unroll
    for (int tap = 0; tap < 9; ++tap) {
      const int kh = tap / 3, kw = tap - kh * 3;
      bf16x8 a[4];
#pragma unroll
      for (int mf = 0; mf < 4; ++mf) {
        int L = (wid * 4 + mf + kh) * 18 + (col + kw);
        int off = (L * 128 + h * 64 + kq * 16) ^ ((L & 7) << 4);
        a[mf] = __builtin_bit_cast(bf16x8, *(const u16x8*)(lds + off));
      }
      bf16x8 w[4];
#pragma unroll
      for (int nf = 0; nf < 4; ++nf) {
        int oc = nf * 16 + col;
        int off = 41472 + oc * 592 + (tap * 4 + kq) * 16;
        w[nf] = __builtin_bit_cast(bf16x8, *(const u16x8*)(lds + off));
      }
#pragma unroll
      for (int mf = 0; mf < 4; ++mf)
#pragma unroll
        for (int nf = 0; nf < 4; ++nf) acc[mf][nf] = mfma16(a[mf], w[nf], acc[mf][nf]);
    }
  }
  const float* bb = bias + b * 64;
#pragma unroll
  for (int mf = 0; mf < 4; ++mf) {
    int y = by0 + wid * 4 + mf;
    if (STAGE == 1) {
      // permuted NHWC: lane's 4 nf values contiguous at ic' = col*4+nf
#pragma unroll
      for (int r = 0; r < 4; ++r) {
        int x = bx0 + kq * 4 + r;
        u32x2 pk;
        pk[0] = (u32)f2bf(fmaxf(acc[mf][0][r] + bb[col], 0.f)) |
                ((u32)f2bf(fmaxf(acc[mf][1][r] + bb[16 + col], 0.f)) << 16);
        pk[1] = (u32)f2bf(fmaxf(acc[mf][2][r] + bb[32 + col], 0.f)) |
                ((u32)f2bf(fmaxf(acc[mf][3][r] + bb[48 + col], 0.f)) << 16);
        *(u32x2*)((u16*)dst + (((size_t)b * 256 + y) * 256 + x) * 64 + col * 4) = pk;
      }
    } else {
#pragma unroll
      for (int nf = 0; nf < 4; ++nf) {
        int oc = nf * 16 + col;
        float bv = bb[oc];
        size_t o = (((size_t)b * 64 + oc) * 256 + y) * 256 + bx0 + kq * 4;
        f32x4 rx = *(const f32x4*)(resid + o);
        f32x4 vv;
#pragma unroll
        for (int r = 0; r < 4; ++r) vv[r] = rx[r] + acc[mf][nf][r] + bv;
        *(f32x4*)((float*)dst + o) = vv;
      }
    }
  }
}

extern "C" void kernel_launch(void* const* d_in, const int* in_sizes, int n_in,
                              void* d_out, int out_size, void* d_ws, size_t ws_size,
                              hipStream_t stream) {
  const float* x        = (const float*)d_in[0];
  const float* ow1      = (const float*)d_in[1];
  const float* ow2      = (const float*)d_in[2];
  const float* cw1      = (const float*)d_in[3];
  const float* cb1      = (const float*)d_in[4];
  const float* cw2      = (const float*)d_in[5];
  const float* cb2      = (const float*)d_in[6];
  const float* cw3      = (const float*)d_in[7];
  const float* cb3      = (const float*)d_in[8];
  const float* scale_w  = (const float*)d_in[9];
  const float* scale_b  = (const float*)d_in[10];
  const float* shift_w  = (const float*)d_in[11];
  const float* shift_b  = (const float*)d_in[12];
  const float* dyn1     = (const float*)d_in[13];
  const float* share1   = (const float*)d_in[14];
  const float* share1_b = (const float*)d_in[15];
  const float* dyn2     = (const float*)d_in[16];
  const float* share2   = (const float*)d_in[17];
  const float* share2_b = (const float*)d_in[18];
  float* out = (float*)d_out;

  char* p = (char*)d_ws;
  u16* xh   = (u16*)p;            p += (size_t)8 * 256 * 256 * 64 * 2;
  u16* midh = (u16*)p;            p += (size_t)8 * 256 * 256 * 64 * 2;
  u16* wbf1 = (u16*)p;            p += (size_t)8 * 64 * 576 * 2;
  u16* wbf2 = (u16*)p;            p += (size_t)8 * 64 * 576 * 2;
  u16* cwb1 = (u16*)p;            p += (size_t)32 * 3200 * 2;
  u16* cwb2 = (u16*)p;            p += (size_t)32 * 288 * 2;
  u16* cwb3 = (u16*)p;            p += (size_t)32 * 288 * 2;
  float* a_    = (float*)p;       p += 512 * 4;
  float* bias1 = (float*)p;       p += 512 * 4;
  float* bias2 = (float*)p;       p += 512 * 4;
  float* cond  = (float*)p;       p += 256 * 4;
  // cond-net temporaries overlap midh (dead before hda1 writes midh)
  u16* h1h = midh;                                   // 8*126*126*32 bf16 (permuted ch)
  u16* h2h = h1h + (size_t)8 * 126 * 126 * 32;       // 8*63*63*32 bf16
  float* h3 = (float*)(h2h + (size_t)8 * 63 * 63 * 32);  // 8*32*32*32 f32

  k_tr<<<dim3(8, 256, 8), 256, 0, stream>>>(x, xh);

  k_prep_cw1<<<(32 * 3200 + 255) / 256, 256, 0, stream>>>(cw1, cwb1);
  k_prep_cw<<<(32 * 288 + 255) / 256, 256, 0, stream>>>(cw2, cwb2, 32, 9, 32 * 288, 1);
  k_prep_cw<<<(32 * 288 + 255) / 256, 256, 0, stream>>>(cw3, cwb3, 32, 9, 32 * 288, 0);

  k_cond1_mfma<<<1024, 256, 0, stream>>>(xh, cwb1, cb1, h1h);
  k_conv_s2<126, 63, 32, 3, 0><<<dim3(4, 8, 8), 256, 0, stream>>>(h1h, cwb2, cb2, h2h);
  k_conv_s2<63, 32, 32, 3, 1><<<dim3(2, 4, 8), 256, 0, stream>>>(h2h, cwb3, cb3, h3);

  k_mean<<<256, 256, 0, stream>>>(h3, cond);
  k_film<<<1, 512, 0, stream>>>(cond, scale_w, scale_b, shift_w, shift_b,
                                share1_b, share2_b, a_, bias1, bias2);

  k_prep_hda<<<(8 * 64 * 576 + 255) / 256, 256, 0, stream>>>(dyn1, ow1, share1, a_, wbf1, 1, 0);
  k_prep_hda<<<(8 * 64 * 576 + 255) / 256, 256, 0, stream>>>(dyn2, ow2, share2, a_, wbf2, 0, 1);

  k_hda_mfma<1><<<2048, 256, 0, stream>>>(xh, wbf1, bias1, nullptr, midh);
  k_hda_mfma<2><<<2048, 256, 0, stream>>>(midh, wbf2, bias2, x, out);
}

// Round 9
// 340.070 us; speedup vs baseline: 1.0485x; 1.0485x over previous
//
#include <hip/hip_runtime.h>

typedef unsigned short u16;
typedef unsigned int u32;
typedef __attribute__((ext_vector_type(8))) __bf16 bf16x8;
typedef __attribute__((ext_vector_type(8))) u16 u16x8;
typedef __attribute__((ext_vector_type(4))) float f32x4;
typedef __attribute__((ext_vector_type(2))) u32 u32x2;

static constexpr size_t PS = (size_t)8 * 256 * 256 * 16;  // channel-plane stride (u16 elems)

__device__ __forceinline__ u16 f2bf(float f) {
  u32 u = __builtin_bit_cast(u32, f);
  u = (u + 0x7FFFu + ((u >> 16) & 1u)) >> 16;
  return (u16)u;
}

__device__ __forceinline__ f32x4 mfma16(bf16x8 a, bf16x8 b, f32x4 c) {
  return __builtin_amdgcn_mfma_f32_16x16x32_bf16(a, b, c, 0, 0, 0);
}

// ---------- NCHW f32 -> 4-plane chunked bf16: [p][b][y][x][16ic] ----------
__global__ __launch_bounds__(256) void k_tr(const float* __restrict__ x,
                                            u16* __restrict__ xh) {
  __shared__ float t[64][33];
  const int b = blockIdx.z, y = blockIdx.y, x0 = blockIdx.x * 32;
  const int tid = threadIdx.x;
  {
    int ic = tid >> 2, xo = (tid & 3) * 8;
    const float* s = x + (((size_t)b * 64 + ic) * 256 + y) * 256 + x0 + xo;
    f32x4 v0 = *(const f32x4*)s;
    f32x4 v1 = *(const f32x4*)(s + 4);
#pragma unroll
    for (int j = 0; j < 4; ++j) { t[ic][xo + j] = v0[j]; t[ic][xo + 4 + j] = v1[j]; }
  }
  __syncthreads();
  {
    int xc = tid & 31, slot = tid >> 5;  // slot 0..7 -> ic0 = slot*8
    int ic0 = slot * 8;
    u16x8 v;
#pragma unroll
    for (int j = 0; j < 8; ++j) v[j] = f2bf(t[ic0 + j][xc]);
    *(u16x8*)(xh + (size_t)(slot >> 1) * PS +
              (((size_t)b * 256 + y) * 256 + x0 + xc) * 16 + (slot & 1) * 8) = v;
  }
}

// ---------- conv2/3 weights: [OC][IC][3][3] f32 -> [oc][tap*IC+icp] bf16 ----------
// perm=1: input channels arrive permuted as icp = (ic&15)*2 + (ic>>4)  (IC=32)
__global__ void k_prep_cw(const float* __restrict__ src, u16* __restrict__ dst,
                          int IC, int KK2, int n, int perm) {
  int d = blockIdx.x * 256 + threadIdx.x;
  if (d >= n) return;
  int per = KK2 * IC;
  int oc = d / per, r = d - oc * per;
  int tap = r / IC, icp = r - tap * IC;
  int ic = perm ? ((icp >> 1) + (icp & 1) * 16) : icp;
  dst[d] = f2bf(src[(oc * IC + ic) * KK2 + tap]);
}

// ---------- conv1 weights: [32][64][7][7] f32 -> [oc][tap(50, zero-pad)][ic(64)] bf16 ----------
__global__ void k_prep_cw1(const float* __restrict__ src, u16* __restrict__ dst) {
  int d = blockIdx.x * 256 + threadIdx.x;  // 32*3200
  if (d >= 32 * 3200) return;
  int oc = d / 3200, r = d - oc * 3200;
  int tap = r >> 6, ic = r & 63;
  float v = (tap < 49) ? src[(oc * 64 + ic) * 49 + tap] : 0.f;
  dst[d] = f2bf(v);
}

// ---------- HDA weights: merge dyn*ow | share (optionally *a) -> [b][oc][576] bf16 ----------
// perm=1 (stage 2): k-slot icp holds real channel ic = (icp&3)*16 + (icp>>2)
__global__ void k_prep_hda(const float* __restrict__ dyn, const float* __restrict__ ow,
                           const float* __restrict__ share, const float* __restrict__ a_,
                           u16* __restrict__ dst, int use_a, int perm) {
  int d = blockIdx.x * 256 + threadIdx.x;
  if (d >= 8 * 64 * 576) return;
  int b = d / 36864, r = d - b * 36864;
  int oc = r / 576, k = r - oc * 576;
  int tap = k >> 6, icp = k & 63;
  int ic = perm ? ((icp & 3) * 16 + (icp >> 2)) : icp;
  float v = (oc < 32) ? dyn[(oc * 64 + ic) * 9 + tap] * ow[((b * 32 + oc) * 64 + ic) * 9 + tap]
                      : share[((oc - 32) * 64 + ic) * 9 + tap];
  if (use_a) v *= a_[b * 64 + oc];
  dst[d] = f2bf(v);
}

// ---------- cond conv1: 7x7 s2 p1 64->32, MFMA, LDS-staged from dense planes ----------
// 16x16 out tile; A chunk = 38x37 pos x 16ic (dense 32B/pixel reads from plane c).
// out: [8][126][126][32] bf16, PERMUTED channel order ic' = col*2 + nf
__global__ __launch_bounds__(256, 3) void k_cond1_mfma(const u16* __restrict__ xh,
    const u16* __restrict__ wgt /*[32][3200]*/, const float* __restrict__ cb,
    u16* __restrict__ dst) {
  __shared__ char lds[45120];  // 38x37=1406 pos x 32B, swizzled
  // bijective XCD swizzle: 512 = 8 XCDs x 64; each XCD owns one batch
  const int wg0 = blockIdx.x;
  const int wg = ((wg0 & 7) << 6) | (wg0 >> 3);
  const int b = wg >> 6, rr = wg & 63;
  const int oh0 = (rr >> 3) << 4, ow0 = (rr & 7) << 4;
  const int tid = threadIdx.x, lane = tid & 63, wid = tid >> 6;
  const int col = lane & 15, kq = lane >> 4;
  const int ihs = 2 * oh0 - 1, iws = 2 * ow0 - 1;
  const u16x8 Z = (u16x8)0;
  f32x4 acc[4][2];
#pragma unroll
  for (int i = 0; i < 4; ++i)
#pragma unroll
    for (int j = 0; j < 2; ++j) acc[i][j] = 0.f;
#pragma unroll 1
  for (int c = 0; c < 4; ++c) {  // 16-ic chunks, each from its dense plane
    const u16* xp = xh + (size_t)c * PS;
    __syncthreads();
    for (int i = tid; i < 2812; i += 256) {  // 1406 pos x 2 halves
      int pos = i >> 1, half = i & 1;
      int r = pos / 37, cc = pos - r * 37;
      int gy = ihs + r, gx = iws + cc;
      u16x8 v = Z;
      if ((unsigned)gy < 256u && (unsigned)gx < 256u)
        v = *(const u16x8*)(xp + (((size_t)b * 256 + gy) * 256 + gx) * 16 + half * 8);
      int off = (pos * 32 + half * 16) ^ (((pos >> 1) & 7) << 4);
      *(u16x8*)(lds + off) = v;
    }
    __syncthreads();
#pragma unroll
    for (int s = 0; s < 25; ++s) {  // K-step: taps 2s (kq<2) | 2s+1 (kq>=2)
      const int t0 = 2 * s, t1 = 2 * s + 1;
      const int kh0 = t0 / 7, kw0 = t0 % 7;
      const int kh1 = t1 / 7, kw1 = t1 % 7;
      int hi = kq >> 1;
      int kh = hi ? kh1 : kh0;
      int kw = hi ? kw1 : kw0;
      int tap = hi ? t1 : t0;
      int hoff = (kq & 1) * 16;
      bf16x8 a[4];
#pragma unroll
      for (int mf = 0; mf < 4; ++mf) {
        int py = wid * 4 + mf;
        int pos = (2 * py + kh) * 37 + 2 * col + kw;
        int off = (pos * 32 + hoff) ^ (((pos >> 1) & 7) << 4);
        a[mf] = __builtin_bit_cast(bf16x8, *(const u16x8*)(lds + off));
      }
      bf16x8 w[2];
#pragma unroll
      for (int nf = 0; nf < 2; ++nf)
        w[nf] = __builtin_bit_cast(bf16x8,
            *(const u16x8*)(wgt + (nf * 16 + col) * 3200 + tap * 64 + c * 16 + (kq & 1) * 8));
#pragma unroll
      for (int mf = 0; mf < 4; ++mf)
#pragma unroll
        for (int nf = 0; nf < 2; ++nf) acc[mf][nf] = mfma16(a[mf], w[nf], acc[mf][nf]);
    }
  }
  const float bv0 = cb[col], bv1 = cb[16 + col];
#pragma unroll
  for (int mf = 0; mf < 4; ++mf) {
    int oh = oh0 + wid * 4 + mf;
    if (oh >= 126) continue;
#pragma unroll
    for (int r = 0; r < 4; ++r) {
      int ow = ow0 + kq * 4 + r;
      if (ow >= 126) continue;
      u32 pack = (u32)f2bf(fmaxf(acc[mf][0][r] + bv0, 0.f)) |
                 ((u32)f2bf(fmaxf(acc[mf][1][r] + bv1, 0.f)) << 16);
      *(u32*)(dst + (((size_t)b * 126 + oh) * 126 + ow) * 32 + col * 2) = pack;
    }
  }
}

// ---------- generic stride-2 pad-1 conv (small conv2/conv3) ----------
template <int HI, int HO, int IC, int KK, int OUTF32>
__global__ __launch_bounds__(256, 4) void k_conv_s2(const u16* __restrict__ src,
    const u16* __restrict__ wgt, const float* __restrict__ bias, void* __restrict__ dst) {
  const int b = blockIdx.z;
  const int by0 = blockIdx.y * 8, bx0 = blockIdx.x * 16;
  const int tid = threadIdx.x, lane = tid & 63, wid = tid >> 6;
  const int col = lane & 15, kq = lane >> 4;
  f32x4 acc[2][2];
#pragma unroll
  for (int i = 0; i < 2; ++i)
#pragma unroll
    for (int j = 0; j < 2; ++j) acc[i][j] = 0.f;
  const u16x8 Z = (u16x8)0;
#pragma unroll
  for (int kh = 0; kh < KK; ++kh) {
#pragma unroll
    for (int kw = 0; kw < KK; ++kw) {
#pragma unroll
      for (int h = 0; h < IC / 32; ++h) {
        bf16x8 a[2];
#pragma unroll
        for (int mf = 0; mf < 2; ++mf) {
          int oh = by0 + wid * 2 + mf;
          int ih = 2 * oh - 1 + kh;
          int ix = 2 * (bx0 + col) - 1 + kw;
          int ic = h * 32 + kq * 8;
          u16x8 raw = Z;
          if ((unsigned)ih < (unsigned)HI && (unsigned)ix < (unsigned)HI)
            raw = *(const u16x8*)(src + (((size_t)b * HI + ih) * HI + ix) * IC + ic);
          a[mf] = __builtin_bit_cast(bf16x8, raw);
        }
        int k0 = (kh * KK + kw) * IC + h * 32 + kq * 8;
        bf16x8 w[2];
#pragma unroll
        for (int nf = 0; nf < 2; ++nf)
          w[nf] = __builtin_bit_cast(bf16x8,
                    *(const u16x8*)(wgt + (size_t)(nf * 16 + col) * (KK * KK * IC) + k0));
#pragma unroll
        for (int mf = 0; mf < 2; ++mf)
#pragma unroll
          for (int nf = 0; nf < 2; ++nf) acc[mf][nf] = mfma16(a[mf], w[nf], acc[mf][nf]);
      }
    }
  }
#pragma unroll
  for (int mf = 0; mf < 2; ++mf) {
    int oh = by0 + wid * 2 + mf;
    if (oh >= HO) continue;
#pragma unroll
    for (int nf = 0; nf < 2; ++nf) {
      int oc = nf * 16 + col;
      float bv = bias[oc];
#pragma unroll
      for (int r = 0; r < 4; ++r) {
        int ow = bx0 + kq * 4 + r;
        if (ow >= HO) continue;
        float v = fmaxf(acc[mf][nf][r] + bv, 0.f);
        if (OUTF32)
          ((float*)dst)[(((size_t)b * 32 + oc) * HO + oh) * HO + ow] = v;
        else
          ((u16*)dst)[(((size_t)b * HO + oh) * HO + ow) * 32 + oc] = f2bf(v);
      }
    }
  }
}

// ---------- mean over 32x32 -> cond[8*32] ----------
__global__ void k_mean(const float* __restrict__ h3, float* __restrict__ cond) {
  int bo = blockIdx.x;
  int tid = threadIdx.x;
  float s = 0.f;
  for (int i = tid; i < 1024; i += 256) s += h3[bo * 1024 + i];
  __shared__ float red[256];
  red[tid] = s;
  __syncthreads();
  for (int o = 128; o > 0; o >>= 1) {
    if (tid < o) red[tid] += red[tid + o];
    __syncthreads();
  }
  if (tid == 0) cond[bo] = red[0] * (1.f / 1024.f);
}

// ---------- FiLM fold ----------
__global__ void k_film(const float* __restrict__ cond,
                       const float* __restrict__ scale_w, const float* __restrict__ scale_b,
                       const float* __restrict__ shift_w, const float* __restrict__ shift_b,
                       const float* __restrict__ share1_b, const float* __restrict__ share2_b,
                       float* __restrict__ a_, float* __restrict__ bias1,
                       float* __restrict__ bias2) {
  int t = threadIdx.x;  // 512
  int b = t >> 6, j = t & 63;
  float s = scale_b[j], sh = shift_b[j];
  for (int k = 0; k < 32; ++k) {
    float c = cond[b * 32 + k];
    s = fmaf(c, scale_w[j * 32 + k], s);
    sh = fmaf(c, shift_w[j * 32 + k], sh);
  }
  float a = s + 1.f;
  float b0 = (j < 32) ? 0.f : share1_b[j - 32];
  a_[t] = a;
  bias1[t] = fmaf(a, b0, sh);
  bias2[t] = (j < 32) ? 0.f : share2_b[j - 32];
}

// ---------- HDA conv 3x3 s1 p1 64->64, MFMA ----------
// A-tile staged from 4 dense planes (18x18x64, 41.5KB LDS) + W half (592B stripes).
// STAGE 1: dst = 4-plane chunked bf16 relu(conv+bias), ic' = col*4+nf -> 8B stores
// STAGE 2: dst = NCHW f32 resid+conv+bias  (weights pre-permuted to match plane order)
template <int STAGE>
__global__ __launch_bounds__(256, 2) void k_hda_mfma(const u16* __restrict__ asrc,
    const u16* __restrict__ wall, const float* __restrict__ bias,
    const float* __restrict__ resid, void* __restrict__ dst) {
  __shared__ char lds[79360];  // [0,41472): A tile; [41472,79360): W half (64 x 592B)
  const int wg0 = blockIdx.x;
  const int wg = ((wg0 & 7) << 8) + (wg0 >> 3);
  const int b = wg >> 8;
  const int rr = wg & 255;
  const int by0 = (rr >> 4) << 4, bx0 = (rr & 15) << 4;
  const int tid = threadIdx.x, lane = tid & 63, wid = tid >> 6;
  const int col = lane & 15, kq = lane >> 4;
  const u16x8 Z = (u16x8)0;
  const u16* wb = wall + (size_t)b * 64 * 576;
  // stage input tile (all 64 ic, from 4 planes)
  for (int i = tid; i < 2592; i += 256) {
    int L = i >> 3, c = i & 7;  // c: 16B slot -> plane c>>1, half c&1
    int yy = L / 18, xx = L - yy * 18;
    int gy = by0 - 1 + yy, gx = bx0 - 1 + xx;
    u16x8 v = Z;
    if ((unsigned)gy < 256u && (unsigned)gx < 256u)
      v = *(const u16x8*)(asrc + (size_t)(c >> 1) * PS +
                          (((size_t)b * 256 + gy) * 256 + gx) * 16 + (c & 1) * 8);
    int off = (L * 128 + c * 16) ^ ((L & 7) << 4);
    *(u16x8*)(lds + off) = v;
  }
  // stage weight half h=0 (592B stripe per oc)
  {
    int i = tid;
#pragma unroll
    for (int it = 0; it < 9; ++it, i += 256) {  // 2304 = 9*256 exact
      int oc = i / 36, s = i - oc * 36;
      int tap = s >> 2, q = s & 3;
      u16x8 v = *(const u16x8*)(wb + oc * 576 + tap * 64 + q * 8);
      int off = 41472 + oc * 592 + s * 16;
      *(u16x8*)(lds + off) = v;
    }
  }
  __syncthreads();
  f32x4 acc[4][4];
#pragma unroll
  for (int i = 0; i < 4; ++i)
#pragma unroll
    for (int j = 0; j < 4; ++j) acc[i][j] = 0.f;
#pragma unroll 1
  for (int h = 0; h < 2; ++h) {
    if (h == 1) {
      __syncthreads();  // h=0 reads done
      int i = tid;
#pragma unroll
      for (int it = 0; it < 9; ++it, i += 256) {
        int oc = i / 36, s = i - oc * 36;
        int tap = s >> 2, q = s & 3;
        u16x8 v = *(const u16x8*)(wb + oc * 576 + tap * 64 + 32 + q * 8);
        int off = 41472 + oc * 592 + s * 16;
        *(u16x8*)(lds + off) = v;
      }
      __syncthreads();
    }
#pragma unroll
    for (int tap = 0; tap < 9; ++tap) {
      const int kh = tap / 3, kw = tap - kh * 3;
      bf16x8 a[4];
#pragma unroll
      for (int mf = 0; mf < 4; ++mf) {
        int L = (wid * 4 + mf + kh) * 18 + (col + kw);
        int off = (L * 128 + h * 64 + kq * 16) ^ ((L & 7) << 4);
        a[mf] = __builtin_bit_cast(bf16x8, *(const u16x8*)(lds + off));
      }
      bf16x8 w[4];
#pragma unroll
      for (int nf = 0; nf < 4; ++nf) {
        int oc = nf * 16 + col;
        int off = 41472 + oc * 592 + (tap * 4 + kq) * 16;
        w[nf] = __builtin_bit_cast(bf16x8, *(const u16x8*)(lds + off));
      }
#pragma unroll
      for (int mf = 0; mf < 4; ++mf)
#pragma unroll
        for (int nf = 0; nf < 4; ++nf) acc[mf][nf] = mfma16(a[mf], w[nf], acc[mf][nf]);
    }
  }
  const float* bb = bias + b * 64;
#pragma unroll
  for (int mf = 0; mf < 4; ++mf) {
    int y = by0 + wid * 4 + mf;
    if (STAGE == 1) {
      // chunked 4-plane store: ic' = col*4+nf -> plane col>>2, off (col&3)*4+nf
#pragma unroll
      for (int r = 0; r < 4; ++r) {
        int x = bx0 + kq * 4 + r;
        u32x2 pk;
        pk[0] = (u32)f2bf(fmaxf(acc[mf][0][r] + bb[col], 0.f)) |
                ((u32)f2bf(fmaxf(acc[mf][1][r] + bb[16 + col], 0.f)) << 16);
        pk[1] = (u32)f2bf(fmaxf(acc[mf][2][r] + bb[32 + col], 0.f)) |
                ((u32)f2bf(fmaxf(acc[mf][3][r] + bb[48 + col], 0.f)) << 16);
        *(u32x2*)((u16*)dst + (size_t)(col >> 2) * PS +
                  (((size_t)b * 256 + y) * 256 + x) * 16 + (col & 3) * 4) = pk;
      }
    } else {
#pragma unroll
      for (int nf = 0; nf < 4; ++nf) {
        int oc = nf * 16 + col;
        float bv = bb[oc];
        size_t o = (((size_t)b * 64 + oc) * 256 + y) * 256 + bx0 + kq * 4;
        f32x4 rx = *(const f32x4*)(resid + o);
        f32x4 vv;
#pragma unroll
        for (int r = 0; r < 4; ++r) vv[r] = rx[r] + acc[mf][nf][r] + bv;
        *(f32x4*)((float*)dst + o) = vv;
      }
    }
  }
}

extern "C" void kernel_launch(void* const* d_in, const int* in_sizes, int n_in,
                              void* d_out, int out_size, void* d_ws, size_t ws_size,
                              hipStream_t stream) {
  const float* x        = (const float*)d_in[0];
  const float* ow1      = (const float*)d_in[1];
  const float* ow2      = (const float*)d_in[2];
  const float* cw1      = (const float*)d_in[3];
  const float* cb1      = (const float*)d_in[4];
  const float* cw2      = (const float*)d_in[5];
  const float* cb2      = (const float*)d_in[6];
  const float* cw3      = (const float*)d_in[7];
  const float* cb3      = (const float*)d_in[8];
  const float* scale_w  = (const float*)d_in[9];
  const float* scale_b  = (const float*)d_in[10];
  const float* shift_w  = (const float*)d_in[11];
  const float* shift_b  = (const float*)d_in[12];
  const float* dyn1     = (const float*)d_in[13];
  const float* share1   = (const float*)d_in[14];
  const float* share1_b = (const float*)d_in[15];
  const float* dyn2     = (const float*)d_in[16];
  const float* share2   = (const float*)d_in[17];
  const float* share2_b = (const float*)d_in[18];
  float* out = (float*)d_out;

  char* p = (char*)d_ws;
  u16* xh   = (u16*)p;            p += (size_t)8 * 256 * 256 * 64 * 2;   // 4 planes
  u16* midh = (u16*)p;            p += (size_t)8 * 256 * 256 * 64 * 2;   // 4 planes
  u16* wbf1 = (u16*)p;            p += (size_t)8 * 64 * 576 * 2;
  u16* wbf2 = (u16*)p;            p += (size_t)8 * 64 * 576 * 2;
  u16* cwb1 = (u16*)p;            p += (size_t)32 * 3200 * 2;
  u16* cwb2 = (u16*)p;            p += (size_t)32 * 288 * 2;
  u16* cwb3 = (u16*)p;            p += (size_t)32 * 288 * 2;
  float* a_    = (float*)p;       p += 512 * 4;
  float* bias1 = (float*)p;       p += 512 * 4;
  float* bias2 = (float*)p;       p += 512 * 4;
  float* cond  = (float*)p;       p += 256 * 4;
  // cond-net temporaries overlap midh (dead before hda1 writes midh)
  u16* h1h = midh;                                   // 8*126*126*32 bf16 (permuted ch)
  u16* h2h = h1h + (size_t)8 * 126 * 126 * 32;       // 8*63*63*32 bf16
  float* h3 = (float*)(h2h + (size_t)8 * 63 * 63 * 32);  // 8*32*32*32 f32

  k_tr<<<dim3(8, 256, 8), 256, 0, stream>>>(x, xh);

  k_prep_cw1<<<(32 * 3200 + 255) / 256, 256, 0, stream>>>(cw1, cwb1);
  k_prep_cw<<<(32 * 288 + 255) / 256, 256, 0, stream>>>(cw2, cwb2, 32, 9, 32 * 288, 1);
  k_prep_cw<<<(32 * 288 + 255) / 256, 256, 0, stream>>>(cw3, cwb3, 32, 9, 32 * 288, 0);

  k_cond1_mfma<<<512, 256, 0, stream>>>(xh, cwb1, cb1, h1h);
  k_conv_s2<126, 63, 32, 3, 0><<<dim3(4, 8, 8), 256, 0, stream>>>(h1h, cwb2, cb2, h2h);
  k_conv_s2<63, 32, 32, 3, 1><<<dim3(2, 4, 8), 256, 0, stream>>>(h2h, cwb3, cb3, h3);

  k_mean<<<256, 256, 0, stream>>>(h3, cond);
  k_film<<<1, 512, 0, stream>>>(cond, scale_w, scale_b, shift_w, shift_b,
                                share1_b, share2_b, a_, bias1, bias2);

  k_prep_hda<<<(8 * 64 * 576 + 255) / 256, 256, 0, stream>>>(dyn1, ow1, share1, a_, wbf1, 1, 0);
  k_prep_hda<<<(8 * 64 * 576 + 255) / 256, 256, 0, stream>>>(dyn2, ow2, share2, a_, wbf2, 0, 1);

  k_hda_mfma<1><<<2048, 256, 0, stream>>>(xh, wbf1, bias1, nullptr, midh);
  k_hda_mfma<2><<<2048, 256, 0, stream>>>(midh, wbf2, bias2, x, out);
}

// Round 10
// 279.800 us; speedup vs baseline: 1.2744x; 1.2154x over previous
//
#include <hip/hip_runtime.h>

typedef unsigned short u16;
typedef unsigned int u32;
typedef __attribute__((ext_vector_type(8))) __bf16 bf16x8;
typedef __attribute__((ext_vector_type(8))) u16 u16x8;
typedef __attribute__((ext_vector_type(4))) float f32x4;
typedef __attribute__((ext_vector_type(2))) u32 u32x2;

static constexpr size_t PS = (size_t)8 * 256 * 256 * 16;  // channel-plane stride (u16 elems)

__device__ __forceinline__ u16 f2bf(float f) {
  u32 u = __builtin_bit_cast(u32, f);
  u = (u + 0x7FFFu + ((u >> 16) & 1u)) >> 16;
  return (u16)u;
}

__device__ __forceinline__ f32x4 mfma16(bf16x8 a, bf16x8 b, f32x4 c) {
  return __builtin_amdgcn_mfma_f32_16x16x32_bf16(a, b, c, 0, 0, 0);
}

// ---------- NCHW f32 -> 4-plane chunked bf16: [p][b][y][x][16ic] ----------
__global__ __launch_bounds__(256) void k_tr(const float* __restrict__ x,
                                            u16* __restrict__ xh) {
  __shared__ float t[64][33];
  const int b = blockIdx.z, y = blockIdx.y, x0 = blockIdx.x * 32;
  const int tid = threadIdx.x;
  {
    int ic = tid >> 2, xo = (tid & 3) * 8;
    const float* s = x + (((size_t)b * 64 + ic) * 256 + y) * 256 + x0 + xo;
    f32x4 v0 = *(const f32x4*)s;
    f32x4 v1 = *(const f32x4*)(s + 4);
#pragma unroll
    for (int j = 0; j < 4; ++j) { t[ic][xo + j] = v0[j]; t[ic][xo + 4 + j] = v1[j]; }
  }
  __syncthreads();
  {
    int xc = tid & 31, slot = tid >> 5;  // slot 0..7 -> ic0 = slot*8
    int ic0 = slot * 8;
    u16x8 v;
#pragma unroll
    for (int j = 0; j < 8; ++j) v[j] = f2bf(t[ic0 + j][xc]);
    *(u16x8*)(xh + (size_t)(slot >> 1) * PS +
              (((size_t)b * 256 + y) * 256 + x0 + xc) * 16 + (slot & 1) * 8) = v;
  }
}

// ---------- conv2/3 weights: [OC][IC][3][3] f32 -> [oc][tap*IC+icp] bf16 ----------
// perm=1: input channels arrive permuted as icp = (ic&15)*2 + (ic>>4)  (IC=32)
__global__ void k_prep_cw(const float* __restrict__ src, u16* __restrict__ dst,
                          int IC, int KK2, int n, int perm) {
  int d = blockIdx.x * 256 + threadIdx.x;
  if (d >= n) return;
  int per = KK2 * IC;
  int oc = d / per, r = d - oc * per;
  int tap = r / IC, icp = r - tap * IC;
  int ic = perm ? ((icp >> 1) + (icp & 1) * 16) : icp;
  dst[d] = f2bf(src[(oc * IC + ic) * KK2 + tap]);
}

// ---------- conv1 weights: [32][64][7][7] f32 -> [8 chunks][32 oc][52 tap][8 ic] bf16 ----------
// chunk h covers ic = h*8 .. h*8+7; taps 49..51 zero-padded
__global__ void k_prep_cw1(const float* __restrict__ src, u16* __restrict__ dst) {
  int d = blockIdx.x * 256 + threadIdx.x;  // 8*32*52*8 = 106496
  if (d >= 106496) return;
  int h = d / 13312, r = d - h * 13312;
  int oc = r / 416, r2 = r - oc * 416;
  int tap = r2 >> 3, i = r2 & 7;
  float v = (tap < 49) ? src[(oc * 64 + h * 8 + i) * 49 + tap] : 0.f;
  dst[d] = f2bf(v);
}

// ---------- HDA weights: merge dyn*ow | share (optionally *a) -> [b][oc][576] bf16 ----------
// perm=1 (stage 2): k-slot icp holds real channel ic = (icp&3)*16 + (icp>>2)
__global__ void k_prep_hda(const float* __restrict__ dyn, const float* __restrict__ ow,
                           const float* __restrict__ share, const float* __restrict__ a_,
                           u16* __restrict__ dst, int use_a, int perm) {
  int d = blockIdx.x * 256 + threadIdx.x;
  if (d >= 8 * 64 * 576) return;
  int b = d / 36864, r = d - b * 36864;
  int oc = r / 576, k = r - oc * 576;
  int tap = k >> 6, icp = k & 63;
  int ic = perm ? ((icp & 3) * 16 + (icp >> 2)) : icp;
  float v = (oc < 32) ? dyn[(oc * 64 + ic) * 9 + tap] * ow[((b * 32 + oc) * 64 + ic) * 9 + tap]
                      : share[((oc - 32) * 64 + ic) * 9 + tap];
  if (use_a) v *= a_[b * 64 + oc];
  dst[d] = f2bf(v);
}

// ---------- cond conv1: 7x7 s2 p1 64->32, MFMA, A AND W both in LDS ----------
// 8 chunks of 8 ic; per chunk: A = 38x37 pos x 16B (swizzled), W = 32oc x 848B stripe.
// Inner loop pure LDS. 49.7KB LDS -> 3 blocks/CU. Grid 512 XCD-swizzled.
// out: [8][126][126][32] bf16, PERMUTED channel order ic' = col*2 + nf
__global__ __launch_bounds__(256, 3) void k_cond1_mfma(const u16* __restrict__ xh,
    const u16* __restrict__ wp /*[8][32][52][8]*/, const float* __restrict__ cb,
    u16* __restrict__ dst) {
  __shared__ char lds[49664];  // [0,22528): A chunk; [22528,49664): W chunk
  // bijective XCD swizzle: 512 = 8 XCDs x 64; each XCD owns one batch
  const int wg0 = blockIdx.x;
  const int wg = ((wg0 & 7) << 6) | (wg0 >> 3);
  const int b = wg >> 6, rr = wg & 63;
  const int oh0 = (rr >> 3) << 4, ow0 = (rr & 7) << 4;
  const int tid = threadIdx.x, lane = tid & 63, wid = tid >> 6;
  const int col = lane & 15, kq = lane >> 4;
  const int ihs = 2 * oh0 - 1, iws = 2 * ow0 - 1;
  const u16x8 Z = (u16x8)0;
  f32x4 acc[4][2];
#pragma unroll
  for (int i = 0; i < 4; ++i)
#pragma unroll
    for (int j = 0; j < 2; ++j) acc[i][j] = 0.f;
  int pb[4];
#pragma unroll
  for (int mf = 0; mf < 4; ++mf) pb[mf] = (2 * (wid * 4 + mf)) * 37 + 2 * col;
  const int wl = 22528 + col * 848 + kq * 16;  // + nf*13568 + s*64
#pragma unroll 1
  for (int h = 0; h < 8; ++h) {
    __syncthreads();
    // stage A chunk (8 ic = half of plane h>>1's 32B pixel)
    for (int i = tid; i < 1406; i += 256) {
      int r = i / 37, cc = i - r * 37;
      int gy = ihs + r, gx = iws + cc;
      u16x8 v = Z;
      if ((unsigned)gy < 256u && (unsigned)gx < 256u)
        v = *(const u16x8*)(xh + (size_t)(h >> 1) * PS +
                            (((size_t)b * 256 + gy) * 256 + gx) * 16 + (h & 1) * 8);
      *(u16x8*)(lds + (i ^ ((i >> 3) & 7)) * 16) = v;
    }
    // stage W chunk: [oc][52 taps x 8ic] -> 848B stripes
    for (int i = tid; i < 1664; i += 256) {
      int oc = i / 52, t = i - oc * 52;
      u16x8 v = *(const u16x8*)(wp + h * 13312 + oc * 416 + t * 8);
      *(u16x8*)(lds + 22528 + oc * 848 + t * 16) = v;
    }
    __syncthreads();
#pragma unroll
    for (int s = 0; s < 13; ++s) {  // taps 4s+kq
      const int t0 = 4 * s;
      const int kh0 = t0 / 7, r7 = t0 % 7;
      int carry = (kq >= 7 - r7) ? 1 : 0;
      int kh = kh0 + carry;
      int kw = r7 + kq - carry * 7;
      int prow = kh * 37 + kw;
      bf16x8 a[4];
#pragma unroll
      for (int mf = 0; mf < 4; ++mf) {
        int pos = pb[mf] + prow;
        int g = pos ^ ((pos >> 3) & 7);
        a[mf] = __builtin_bit_cast(bf16x8, *(const u16x8*)(lds + g * 16));
      }
      bf16x8 w[2];
#pragma unroll
      for (int nf = 0; nf < 2; ++nf)
        w[nf] = __builtin_bit_cast(bf16x8, *(const u16x8*)(lds + wl + nf * 13568 + s * 64));
#pragma unroll
      for (int mf = 0; mf < 4; ++mf)
#pragma unroll
        for (int nf = 0; nf < 2; ++nf) acc[mf][nf] = mfma16(a[mf], w[nf], acc[mf][nf]);
    }
  }
  const float bv0 = cb[col], bv1 = cb[16 + col];
#pragma unroll
  for (int mf = 0; mf < 4; ++mf) {
    int oh = oh0 + wid * 4 + mf;
    if (oh >= 126) continue;
#pragma unroll
    for (int r = 0; r < 4; ++r) {
      int ow = ow0 + kq * 4 + r;
      if (ow >= 126) continue;
      u32 pack = (u32)f2bf(fmaxf(acc[mf][0][r] + bv0, 0.f)) |
                 ((u32)f2bf(fmaxf(acc[mf][1][r] + bv1, 0.f)) << 16);
      *(u32*)(dst + (((size_t)b * 126 + oh) * 126 + ow) * 32 + col * 2) = pack;
    }
  }
}

// ---------- generic stride-2 pad-1 conv (small conv2/conv3) ----------
template <int HI, int HO, int IC, int KK, int OUTF32>
__global__ __launch_bounds__(256, 4) void k_conv_s2(const u16* __restrict__ src,
    const u16* __restrict__ wgt, const float* __restrict__ bias, void* __restrict__ dst) {
  const int b = blockIdx.z;
  const int by0 = blockIdx.y * 8, bx0 = blockIdx.x * 16;
  const int tid = threadIdx.x, lane = tid & 63, wid = tid >> 6;
  const int col = lane & 15, kq = lane >> 4;
  f32x4 acc[2][2];
#pragma unroll
  for (int i = 0; i < 2; ++i)
#pragma unroll
    for (int j = 0; j < 2; ++j) acc[i][j] = 0.f;
  const u16x8 Z = (u16x8)0;
#pragma unroll
  for (int kh = 0; kh < KK; ++kh) {
#pragma unroll
    for (int kw = 0; kw < KK; ++kw) {
#pragma unroll
      for (int h = 0; h < IC / 32; ++h) {
        bf16x8 a[2];
#pragma unroll
        for (int mf = 0; mf < 2; ++mf) {
          int oh = by0 + wid * 2 + mf;
          int ih = 2 * oh - 1 + kh;
          int ix = 2 * (bx0 + col) - 1 + kw;
          int ic = h * 32 + kq * 8;
          u16x8 raw = Z;
          if ((unsigned)ih < (unsigned)HI && (unsigned)ix < (unsigned)HI)
            raw = *(const u16x8*)(src + (((size_t)b * HI + ih) * HI + ix) * IC + ic);
          a[mf] = __builtin_bit_cast(bf16x8, raw);
        }
        int k0 = (kh * KK + kw) * IC + h * 32 + kq * 8;
        bf16x8 w[2];
#pragma unroll
        for (int nf = 0; nf < 2; ++nf)
          w[nf] = __builtin_bit_cast(bf16x8,
                    *(const u16x8*)(wgt + (size_t)(nf * 16 + col) * (KK * KK * IC) + k0));
#pragma unroll
        for (int mf = 0; mf < 2; ++mf)
#pragma unroll
          for (int nf = 0; nf < 2; ++nf) acc[mf][nf] = mfma16(a[mf], w[nf], acc[mf][nf]);
      }
    }
  }
#pragma unroll
  for (int mf = 0; mf < 2; ++mf) {
    int oh = by0 + wid * 2 + mf;
    if (oh >= HO) continue;
#pragma unroll
    for (int nf = 0; nf < 2; ++nf) {
      int oc = nf * 16 + col;
      float bv = bias[oc];
#pragma unroll
      for (int r = 0; r < 4; ++r) {
        int ow = bx0 + kq * 4 + r;
        if (ow >= HO) continue;
        float v = fmaxf(acc[mf][nf][r] + bv, 0.f);
        if (OUTF32)
          ((float*)dst)[(((size_t)b * 32 + oc) * HO + oh) * HO + ow] = v;
        else
          ((u16*)dst)[(((size_t)b * HO + oh) * HO + ow) * 32 + oc] = f2bf(v);
      }
    }
  }
}

// ---------- mean over 32x32 -> cond[8*32] ----------
__global__ void k_mean(const float* __restrict__ h3, float* __restrict__ cond) {
  int bo = blockIdx.x;
  int tid = threadIdx.x;
  float s = 0.f;
  for (int i = tid; i < 1024; i += 256) s += h3[bo * 1024 + i];
  __shared__ float red[256];
  red[tid] = s;
  __syncthreads();
  for (int o = 128; o > 0; o >>= 1) {
    if (tid < o) red[tid] += red[tid + o];
    __syncthreads();
  }
  if (tid == 0) cond[bo] = red[0] * (1.f / 1024.f);
}

// ---------- FiLM fold ----------
__global__ void k_film(const float* __restrict__ cond,
                       const float* __restrict__ scale_w, const float* __restrict__ scale_b,
                       const float* __restrict__ shift_w, const float* __restrict__ shift_b,
                       const float* __restrict__ share1_b, const float* __restrict__ share2_b,
                       float* __restrict__ a_, float* __restrict__ bias1,
                       float* __restrict__ bias2) {
  int t = threadIdx.x;  // 512
  int b = t >> 6, j = t & 63;
  float s = scale_b[j], sh = shift_b[j];
  for (int k = 0; k < 32; ++k) {
    float c = cond[b * 32 + k];
    s = fmaf(c, scale_w[j * 32 + k], s);
    sh = fmaf(c, shift_w[j * 32 + k], sh);
  }
  float a = s + 1.f;
  float b0 = (j < 32) ? 0.f : share1_b[j - 32];
  a_[t] = a;
  bias1[t] = fmaf(a, b0, sh);
  bias2[t] = (j < 32) ? 0.f : share2_b[j - 32];
}

// ---------- HDA conv 3x3 s1 p1 64->64, MFMA ----------
// A-tile staged from 4 dense planes (18x18x64, 41.5KB LDS) + W half (592B stripes).
// STAGE 1: dst = 4-plane chunked bf16 relu(conv+bias), ic' = col*4+nf -> 8B stores
// STAGE 2: dst = NCHW f32 resid+conv+bias  (weights pre-permuted to match plane order)
template <int STAGE>
__global__ __launch_bounds__(256, 2) void k_hda_mfma(const u16* __restrict__ asrc,
    const u16* __restrict__ wall, const float* __restrict__ bias,
    const float* __restrict__ resid, void* __restrict__ dst) {
  __shared__ char lds[79360];  // [0,41472): A tile; [41472,79360): W half (64 x 592B)
  const int wg0 = blockIdx.x;
  const int wg = ((wg0 & 7) << 8) + (wg0 >> 3);
  const int b = wg >> 8;
  const int rr = wg & 255;
  const int by0 = (rr >> 4) << 4, bx0 = (rr & 15) << 4;
  const int tid = threadIdx.x, lane = tid & 63, wid = tid >> 6;
  const int col = lane & 15, kq = lane >> 4;
  const u16x8 Z = (u16x8)0;
  const u16* wb = wall + (size_t)b * 64 * 576;
  // stage input tile (all 64 ic, from 4 planes)
  for (int i = tid; i < 2592; i += 256) {
    int L = i >> 3, c = i & 7;  // c: 16B slot -> plane c>>1, half c&1
    int yy = L / 18, xx = L - yy * 18;
    int gy = by0 - 1 + yy, gx = bx0 - 1 + xx;
    u16x8 v = Z;
    if ((unsigned)gy < 256u && (unsigned)gx < 256u)
      v = *(const u16x8*)(asrc + (size_t)(c >> 1) * PS +
                          (((size_t)b * 256 + gy) * 256 + gx) * 16 + (c & 1) * 8);
    int off = (L * 128 + c * 16) ^ ((L & 7) << 4);
    *(u16x8*)(lds + off) = v;
  }
  // stage weight half h=0 (592B stripe per oc)
  {
    int i = tid;
#pragma unroll
    for (int it = 0; it < 9; ++it, i += 256) {  // 2304 = 9*256 exact
      int oc = i / 36, s = i - oc * 36;
      int tap = s >> 2, q = s & 3;
      u16x8 v = *(const u16x8*)(wb + oc * 576 + tap * 64 + q * 8);
      int off = 41472 + oc * 592 + s * 16;
      *(u16x8*)(lds + off) = v;
    }
  }
  __syncthreads();
  f32x4 acc[4][4];
#pragma unroll
  for (int i = 0; i < 4; ++i)
#pragma unroll
    for (int j = 0; j < 4; ++j) acc[i][j] = 0.f;
#pragma unroll 1
  for (int h = 0; h < 2; ++h) {
    if (h == 1) {
      __syncthreads();  // h=0 reads done
      int i = tid;
#pragma unroll
      for (int it = 0; it < 9; ++it, i += 256) {
        int oc = i / 36, s = i - oc * 36;
        int tap = s >> 2, q = s & 3;
        u16x8 v = *(const u16x8*)(wb + oc * 576 + tap * 64 + 32 + q * 8);
        int off = 41472 + oc * 592 + s * 16;
        *(u16x8*)(lds + off) = v;
      }
      __syncthreads();
    }
#pragma unroll
    for (int tap = 0; tap < 9; ++tap) {
      const int kh = tap / 3, kw = tap - kh * 3;
      bf16x8 a[4];
#pragma unroll
      for (int mf = 0; mf < 4; ++mf) {
        int L = (wid * 4 + mf + kh) * 18 + (col + kw);
        int off = (L * 128 + h * 64 + kq * 16) ^ ((L & 7) << 4);
        a[mf] = __builtin_bit_cast(bf16x8, *(const u16x8*)(lds + off));
      }
      bf16x8 w[4];
#pragma unroll
      for (int nf = 0; nf < 4; ++nf) {
        int oc = nf * 16 + col;
        int off = 41472 + oc * 592 + (tap * 4 + kq) * 16;
        w[nf] = __builtin_bit_cast(bf16x8, *(const u16x8*)(lds + off));
      }
#pragma unroll
      for (int mf = 0; mf < 4; ++mf)
#pragma unroll
        for (int nf = 0; nf < 4; ++nf) acc[mf][nf] = mfma16(a[mf], w[nf], acc[mf][nf]);
    }
  }
  const float* bb = bias + b * 64;
#pragma unroll
  for (int mf = 0; mf < 4; ++mf) {
    int y = by0 + wid * 4 + mf;
    if (STAGE == 1) {
      // chunked 4-plane store: ic' = col*4+nf -> plane col>>2, off (col&3)*4+nf
#pragma unroll
      for (int r = 0; r < 4; ++r) {
        int x = bx0 + kq * 4 + r;
        u32x2 pk;
        pk[0] = (u32)f2bf(fmaxf(acc[mf][0][r] + bb[col], 0.f)) |
                ((u32)f2bf(fmaxf(acc[mf][1][r] + bb[16 + col], 0.f)) << 16);
        pk[1] = (u32)f2bf(fmaxf(acc[mf][2][r] + bb[32 + col], 0.f)) |
                ((u32)f2bf(fmaxf(acc[mf][3][r] + bb[48 + col], 0.f)) << 16);
        *(u32x2*)((u16*)dst + (size_t)(col >> 2) * PS +
                  (((size_t)b * 256 + y) * 256 + x) * 16 + (col & 3) * 4) = pk;
      }
    } else {
#pragma unroll
      for (int nf = 0; nf < 4; ++nf) {
        int oc = nf * 16 + col;
        float bv = bb[oc];
        size_t o = (((size_t)b * 64 + oc) * 256 + y) * 256 + bx0 + kq * 4;
        f32x4 rx = *(const f32x4*)(resid + o);
        f32x4 vv;
#pragma unroll
        for (int r = 0; r < 4; ++r) vv[r] = rx[r] + acc[mf][nf][r] + bv;
        *(f32x4*)((float*)dst + o) = vv;
      }
    }
  }
}

extern "C" void kernel_launch(void* const* d_in, const int* in_sizes, int n_in,
                              void* d_out, int out_size, void* d_ws, size_t ws_size,
                              hipStream_t stream) {
  const float* x        = (const float*)d_in[0];
  const float* ow1      = (const float*)d_in[1];
  const float* ow2      = (const float*)d_in[2];
  const float* cw1      = (const float*)d_in[3];
  const float* cb1      = (const float*)d_in[4];
  const float* cw2      = (const float*)d_in[5];
  const float* cb2      = (const float*)d_in[6];
  const float* cw3      = (const float*)d_in[7];
  const float* cb3      = (const float*)d_in[8];
  const float* scale_w  = (const float*)d_in[9];
  const float* scale_b  = (const float*)d_in[10];
  const float* shift_w  = (const float*)d_in[11];
  const float* shift_b  = (const float*)d_in[12];
  const float* dyn1     = (const float*)d_in[13];
  const float* share1   = (const float*)d_in[14];
  const float* share1_b = (const float*)d_in[15];
  const float* dyn2     = (const float*)d_in[16];
  const float* share2   = (const float*)d_in[17];
  const float* share2_b = (const float*)d_in[18];
  float* out = (float*)d_out;

  char* p = (char*)d_ws;
  u16* xh   = (u16*)p;            p += (size_t)8 * 256 * 256 * 64 * 2;   // 4 planes
  u16* midh = (u16*)p;            p += (size_t)8 * 256 * 256 * 64 * 2;   // 4 planes
  u16* wbf1 = (u16*)p;            p += (size_t)8 * 64 * 576 * 2;
  u16* wbf2 = (u16*)p;            p += (size_t)8 * 64 * 576 * 2;
  u16* cwb1 = (u16*)p;            p += (size_t)106496 * 2;
  u16* cwb2 = (u16*)p;            p += (size_t)32 * 288 * 2;
  u16* cwb3 = (u16*)p;            p += (size_t)32 * 288 * 2;
  float* a_    = (float*)p;       p += 512 * 4;
  float* bias1 = (float*)p;       p += 512 * 4;
  float* bias2 = (float*)p;       p += 512 * 4;
  float* cond  = (float*)p;       p += 256 * 4;
  // cond-net temporaries overlap midh (dead before hda1 writes midh)
  u16* h1h = midh;                                   // 8*126*126*32 bf16 (permuted ch)
  u16* h2h = h1h + (size_t)8 * 126 * 126 * 32;       // 8*63*63*32 bf16
  float* h3 = (float*)(h2h + (size_t)8 * 63 * 63 * 32);  // 8*32*32*32 f32

  k_tr<<<dim3(8, 256, 8), 256, 0, stream>>>(x, xh);

  k_prep_cw1<<<(106496 + 255) / 256, 256, 0, stream>>>(cw1, cwb1);
  k_prep_cw<<<(32 * 288 + 255) / 256, 256, 0, stream>>>(cw2, cwb2, 32, 9, 32 * 288, 1);
  k_prep_cw<<<(32 * 288 + 255) / 256, 256, 0, stream>>>(cw3, cwb3, 32, 9, 32 * 288, 0);

  k_cond1_mfma<<<512, 256, 0, stream>>>(xh, cwb1, cb1, h1h);
  k_conv_s2<126, 63, 32, 3, 0><<<dim3(4, 8, 8), 256, 0, stream>>>(h1h, cwb2, cb2, h2h);
  k_conv_s2<63, 32, 32, 3, 1><<<dim3(2, 4, 8), 256, 0, stream>>>(h2h, cwb3, cb3, h3);

  k_mean<<<256, 256, 0, stream>>>(h3, cond);
  k_film<<<1, 512, 0, stream>>>(cond, scale_w, scale_b, shift_w, shift_b,
                                share1_b, share2_b, a_, bias1, bias2);

  k_prep_hda<<<(8 * 64 * 576 + 255) / 256, 256, 0, stream>>>(dyn1, ow1, share1, a_, wbf1, 1, 0);
  k_prep_hda<<<(8 * 64 * 576 + 255) / 256, 256, 0, stream>>>(dyn2, ow2, share2, a_, wbf2, 0, 1);

  k_hda_mfma<1><<<2048, 256, 0, stream>>>(xh, wbf1, bias1, nullptr, midh);
  k_hda_mfma<2><<<2048, 256, 0, stream>>>(midh, wbf2, bias2, x, out);
}